// Round 2
// baseline (103.707 us; speedup 1.0000x reference)
//
#include <hip/hip_runtime.h>

#define NBINS 10
#define C 10

constexpr int BLOCK = 256;
constexpr int GRID  = 2048;

// Exact f32 bin edges: float32(np.arange(0,1.1,0.1)[t]) == (float)(0.1*t) for t=0..9.
__device__ __constant__ const float E0=0.0f, E1=0.1f, E2=0.2f, E3=0.3f, E4=0.4f,
                                    E5=0.5f, E6=0.6f, E7=0.7f, E8=0.8f, E9=0.9f;

__global__ __launch_bounds__(BLOCK) void ece_main(
    const float* __restrict__ probs,
    const int*   __restrict__ labels,
    double*       __restrict__ g_conf,   // S_t totals (cumulative conf sums)
    unsigned int* __restrict__ g_cnt,    // G_t totals (cumulative counts)
    unsigned int* __restrict__ g_cor,    // per-bin correct counts (direct)
    int npairs)
{
    __shared__ unsigned int s_cor[NBINS];
    __shared__ float        s_conf_red[4 * NBINS];
    __shared__ unsigned int s_cnt_red [4 * NBINS];

    const int tid = threadIdx.x;
    if (tid < NBINS) s_cor[tid] = 0u;
    __syncthreads();

    const float EDGE[NBINS] = {E0,E1,E2,E3,E4,E5,E6,E7,E8,E9};

    unsigned int cnt[NBINS];
    float        conf[NBINS];
#pragma unroll
    for (int t = 0; t < NBINS; ++t) { cnt[t] = 0u; conf[t] = 0.0f; }

    const float4* p4 = reinterpret_cast<const float4*>(probs);
    const int2*   l2 = reinterpret_cast<const int2*>(labels);

    for (int ip = blockIdx.x * BLOCK + tid; ip < npairs; ip += GRID * BLOCK) {
        const size_t b4 = (size_t)ip * 5;
        const float4 q0 = p4[b4+0], q1 = p4[b4+1], q2 = p4[b4+2],
                     q3 = p4[b4+3], q4 = p4[b4+4];
        const int2 lab = l2[ip];

        const float a[C] = {q0.x,q0.y,q0.z,q0.w, q1.x,q1.y,q1.z,q1.w, q2.x,q2.y};
        const float b[C] = {q2.z,q2.w, q3.x,q3.y,q3.z,q3.w, q4.x,q4.y,q4.z,q4.w};

#pragma unroll
        for (int s = 0; s < 2; ++s) {
            const float* p = (s == 0) ? a : b;       // unrolled -> static
            const int  lbl = (s == 0) ? lab.x : lab.y;

            // argmax, first-occurrence ties (matches jnp.argmax)
            float mx = p[0]; int arg = 0;
#pragma unroll
            for (int j = 1; j < C; ++j) {
                if (p[j] > mx) { mx = p[j]; arg = j; }
            }

            // cumulative histogram: G_t / S_t in registers, static indexing only
#pragma unroll
            for (int t = 0; t < NBINS; ++t) {
#pragma unroll
                for (int j = 0; j < C; ++j) {
                    const bool g = p[j] > EDGE[t];
                    cnt[t]  += g ? 1u : 0u;
                    conf[t] += g ? p[j] : 0.0f;
                }
            }

            // correct sample: true-class prob == mx when arg == lbl
            int im = -1;
#pragma unroll
            for (int t = 0; t < NBINS; ++t) im += (mx > EDGE[t]) ? 1 : 0;
            if (arg == lbl) atomicAdd(&s_cor[im], 1u);
        }
    }

    // 64-lane butterfly reduce each accumulator
#pragma unroll
    for (int t = 0; t < NBINS; ++t) {
        for (int o = 32; o > 0; o >>= 1) {
            cnt[t]  += __shfl_xor(cnt[t],  o, 64);
            conf[t] += __shfl_xor(conf[t], o, 64);
        }
    }

    const int wave = tid >> 6, lane = tid & 63;
    if (lane == 0) {
#pragma unroll
        for (int t = 0; t < NBINS; ++t) {
            s_cnt_red [wave * NBINS + t] = cnt[t];
            s_conf_red[wave * NBINS + t] = conf[t];
        }
    }
    __syncthreads();

    if (tid < NBINS) {
        unsigned int c = 0; float f = 0.0f;
#pragma unroll
        for (int w = 0; w < 4; ++w) {
            c += s_cnt_red [w * NBINS + tid];
            f += s_conf_red[w * NBINS + tid];
        }
        atomicAdd(&g_cnt [tid], c);
        atomicAdd(&g_conf[tid], (double)f);
        atomicAdd(&g_cor [tid], s_cor[tid]);
    }
}

__global__ void ece_final(const double* __restrict__ g_conf,
                          const unsigned int* __restrict__ g_cnt,
                          const unsigned int* __restrict__ g_cor,
                          float* __restrict__ out)
{
    if (threadIdx.x == 0 && blockIdx.x == 0) {
        const float edges[11] = {0.0f,0.1f,0.2f,0.3f,0.4f,0.5f,
                                 0.6f,0.7f,0.8f,0.9f,1.0f};
        double total = 0.0, ece = 0.0;
        for (int j = 0; j < NBINS; ++j) {
            // convert cumulative G_t/S_t to per-bin counts/sums
            const double c  = (double)g_cnt[j]  - (j < 9 ? (double)g_cnt[j+1]  : 0.0);
            const double sc = g_conf[j]         - (j < 9 ? g_conf[j+1]         : 0.0);
            const double ba = (double)g_cor[j] / c;
            total += c;
            ece   += fabs(sc / c - ba) * c;
            out[1 + j]  = edges[j + 1] - 0.05f;   // bin centers
            out[11 + j] = (float)ba;              // bin accuracy
        }
        out[0] = (float)(ece / total);
    }
}

extern "C" void kernel_launch(void* const* d_in, const int* in_sizes, int n_in,
                              void* d_out, int out_size, void* d_ws, size_t ws_size,
                              hipStream_t stream)
{
    const float* probs  = (const float*)d_in[0];
    const int*   labels = (const int*)  d_in[1];
    float*       out    = (float*)d_out;
    const int n      = in_sizes[1];   // N_SAMPLES (even)
    const int npairs = n / 2;

    // ws layout: [0,80) double S_t[10] | [80,120) uint G_t[10] | [120,160) uint cor[10]
    double*       g_conf = (double*)d_ws;
    unsigned int* g_cnt  = (unsigned int*)((char*)d_ws + 80);
    unsigned int* g_cor  = (unsigned int*)((char*)d_ws + 120);

    hipMemsetAsync(d_ws, 0, 160, stream);   // ws is not re-poisoned between replays
    ece_main<<<GRID, BLOCK, 0, stream>>>(probs, labels, g_conf, g_cnt, g_cor, npairs);
    ece_final<<<1, 64, 0, stream>>>(g_conf, g_cnt, g_cor, out);
}